// Round 4
// baseline (970.043 us; speedup 1.0000x reference)
//
#include <hip/hip_runtime.h>

using u16 = unsigned short;
using u32 = unsigned int;

typedef __bf16 bf16x8 __attribute__((ext_vector_type(8)));
typedef float  f32x4  __attribute__((ext_vector_type(4)));
typedef _Float16 f16;
typedef _Float16 f16x4 __attribute__((ext_vector_type(4)));
typedef _Float16 f16x8 __attribute__((ext_vector_type(8)));

__device__ __forceinline__ float b2f(u16 u) { return __uint_as_float(((u32)u) << 16); }
__device__ __forceinline__ u16 f2b(float f) {
    u32 u = __float_as_uint(f);
    return (u16)((u + 0x7FFFu + ((u >> 16) & 1u)) >> 16);  // RNE
}

// fp32x8 -> (hi, lo) bf16x8 planes; hi+lo == input to ~2^-18 rel.
__device__ __forceinline__ void split8(f32x4 a0, f32x4 a1, bf16x8& hi, bf16x8& lo) {
    union { bf16x8 v; u16 s[8]; } H, L;
#pragma unroll
    for (int j = 0; j < 4; j++) {
        float f = a0[j]; u16 hb = f2b(f); H.s[j] = hb;     L.s[j] = f2b(f - b2f(hb));
        float g = a1[j]; u16 gb = f2b(g); H.s[4 + j] = gb; L.s[4 + j] = f2b(g - b2f(gb));
    }
    hi = H.v; lo = L.v;
}
__device__ __forceinline__ f16x8 cvt8h(f32x4 a0, f32x4 a1) {
    f16x8 r;
#pragma unroll
    for (int j = 0; j < 4; j++) { r[j] = (f16)a0[j]; r[4 + j] = (f16)a1[j]; }
    return r;
}

// ---------------------------------------------------------------------------
// Fused q projection: q = x@Wq^T + qb (split-bf16 MFMA, fp32-accurate),
// then per-head L2 norm, * exp(min(smul,ln100)), RoPE (freqs_cis input).
// Wave = 64 rows x one head (64 cols). Output fp16 [B*L, 1024].
// Layouts (m89/m91): A lane holds A[m=lane&15][k=quad*8+j];
// C/D row=quad*4+reg, col=lane&15.
// ---------------------------------------------------------------------------
__global__ __launch_bounds__(256) void gemm_q(const float* __restrict__ x,
                                              const float* __restrict__ Wq,
                                              const float* __restrict__ qb,
                                              const float* __restrict__ fc,
                                              const float* __restrict__ smul,
                                              f16* __restrict__ qout) {
    const int K = 1024, L = 1704;
    int lane = threadIdx.x & 63, wv = threadIdx.x >> 6;
    int mt = blockIdx.x >> 2;
    int h  = (blockIdx.x & 3) * 4 + wv;
    int lr = lane & 15, quad = lane >> 4;
    long m0 = (long)mt * 64;

    const float* arow[4];
    const float* wrow[4];
#pragma unroll
    for (int i = 0; i < 4; i++) {
        arow[i] = x  + (m0 + i * 16 + lr) * K + quad * 8;
        wrow[i] = Wq + ((long)(h * 64 + i * 16 + lr)) * K + quad * 8;
    }

    f32x4 acc[4][4] = {};
    for (int ks = 0; ks < 32; ks++) {
        bf16x8 ah[4], al[4], wh[4], wl[4];
#pragma unroll
        for (int i = 0; i < 4; i++) {
            const float* ap = arow[i] + ks * 32;
            split8(*(const f32x4*)ap, *(const f32x4*)(ap + 4), ah[i], al[i]);
            const float* wp = wrow[i] + ks * 32;
            split8(*(const f32x4*)wp, *(const f32x4*)(wp + 4), wh[i], wl[i]);
        }
#pragma unroll
        for (int mi = 0; mi < 4; mi++)
#pragma unroll
            for (int ni = 0; ni < 4; ni++) {
                acc[mi][ni] = __builtin_amdgcn_mfma_f32_16x16x32_bf16(ah[mi], wh[ni], acc[mi][ni], 0, 0, 0);
                acc[mi][ni] = __builtin_amdgcn_mfma_f32_16x16x32_bf16(al[mi], wh[ni], acc[mi][ni], 0, 0, 0);
                acc[mi][ni] = __builtin_amdgcn_mfma_f32_16x16x32_bf16(ah[mi], wl[ni], acc[mi][ni], 0, 0, 0);
            }
    }

    float sm = __expf(fminf(smul[h], 4.6051702f));  // ln(100)
#pragma unroll
    for (int mi = 0; mi < 4; mi++) {
#pragma unroll
        for (int r = 0; r < 4; r++) {
            long rowg = m0 + mi * 16 + quad * 4 + r;
            float v[4];
            float ss = 0.f;
#pragma unroll
            for (int ni = 0; ni < 4; ni++) {
                v[ni] = acc[mi][ni][r] + qb[h * 64 + ni * 16 + lr];
                ss += v[ni] * v[ni];
            }
            ss += __shfl_xor(ss, 1, 64); ss += __shfl_xor(ss, 2, 64);
            ss += __shfl_xor(ss, 4, 64); ss += __shfl_xor(ss, 8, 64);
            float inv = sm / fmaxf(sqrtf(ss), 1e-12f);
            int l = (int)(rowg % L);
            f16* orow = qout + rowg * 1024 + h * 64;
#pragma unroll
            for (int ni = 0; ni < 4; ni++) {
                float u = v[ni] * inv;
                int d = ni * 16 + lr;
                int j = d >> 1;
                float c = fc[(l * 32 + j) * 2];
                float s = fc[(l * 32 + j) * 2 + 1];
                float pr = __shfl_xor(u, 1, 64);
                float o = (lane & 1) ? (pr * s + u * c) : (u * c - pr * s);
                orow[d] = (f16)o;
            }
        }
    }
}

// freqs for cross RoPE: 10000^(-f/16) = 10^(-f/4)
__constant__ double FREQS16[16] = {
    1.0, 0.5623413251903491, 0.31622776601683794, 0.17782794100389228,
    0.1, 0.05623413251903491, 0.03162277660168379, 0.017782794100389228,
    0.01, 0.005623413251903491, 0.0031622776601683794, 0.0017782794100389228,
    0.001, 0.0005623413251903491, 0.00031622776601683794, 0.00017782794100389228};

// ---------------------------------------------------------------------------
// Fused kv projection: kv = y@Wkv^T (split-bf16 MFMA). n-tiles 0..15 = k
// (L2-norm + cross RoPE from 12x12 grid, inline); 16..31 = v (+v_bias).
// Outputs fp32 [B,H,144,64].
// ---------------------------------------------------------------------------
__global__ __launch_bounds__(256) void gemm_kv(const float* __restrict__ y,
                                               const float* __restrict__ Wkv,
                                               const float* __restrict__ vb,
                                               float* __restrict__ kout,
                                               float* __restrict__ vout) {
    const int K = 1024;
    int lane = threadIdx.x & 63, wv = threadIdx.x >> 6;
    int mt = blockIdx.x >> 3;
    int nt = (blockIdx.x & 7) * 4 + wv;
    int lr = lane & 15, quad = lane >> 4;
    long m0 = (long)mt * 64;

    const float* arow[4];
    const float* wrow[4];
#pragma unroll
    for (int i = 0; i < 4; i++) {
        arow[i] = y   + (m0 + i * 16 + lr) * K + quad * 8;
        wrow[i] = Wkv + ((long)(nt * 64 + i * 16 + lr)) * K + quad * 8;
    }

    f32x4 acc[4][4] = {};
    for (int ks = 0; ks < 32; ks++) {
        bf16x8 ah[4], al[4], wh[4], wl[4];
#pragma unroll
        for (int i = 0; i < 4; i++) {
            const float* ap = arow[i] + ks * 32;
            split8(*(const f32x4*)ap, *(const f32x4*)(ap + 4), ah[i], al[i]);
            const float* wp = wrow[i] + ks * 32;
            split8(*(const f32x4*)wp, *(const f32x4*)(wp + 4), wh[i], wl[i]);
        }
#pragma unroll
        for (int mi = 0; mi < 4; mi++)
#pragma unroll
            for (int ni = 0; ni < 4; ni++) {
                acc[mi][ni] = __builtin_amdgcn_mfma_f32_16x16x32_bf16(ah[mi], wh[ni], acc[mi][ni], 0, 0, 0);
                acc[mi][ni] = __builtin_amdgcn_mfma_f32_16x16x32_bf16(al[mi], wh[ni], acc[mi][ni], 0, 0, 0);
                acc[mi][ni] = __builtin_amdgcn_mfma_f32_16x16x32_bf16(ah[mi], wl[ni], acc[mi][ni], 0, 0, 0);
            }
    }

    bool isv = nt >= 16;
    int h = isv ? nt - 16 : nt;
#pragma unroll
    for (int mi = 0; mi < 4; mi++) {
#pragma unroll
        for (int r = 0; r < 4; r++) {
            long row = m0 + mi * 16 + quad * 4 + r;  // [0,1152)
            int b = (int)(row / 144), lk = (int)(row % 144);
            float v[4];
#pragma unroll
            for (int ni = 0; ni < 4; ni++)
                v[ni] = acc[mi][ni][r] + (isv ? vb[h * 64 + ni * 16 + lr] : 0.f);
            float* obase = (isv ? vout : kout) + (((long)(b * 16 + h)) * 144 + lk) * 64;
            if (!isv) {
                float ss = v[0] * v[0] + v[1] * v[1] + v[2] * v[2] + v[3] * v[3];
                ss += __shfl_xor(ss, 1, 64); ss += __shfl_xor(ss, 2, 64);
                ss += __shfl_xor(ss, 4, 64); ss += __shfl_xor(ss, 8, 64);
                float inv = 1.f / fmaxf(sqrtf(ss), 1e-12f);
#pragma unroll
                for (int ni = 0; ni < 4; ni++) {
                    float u = v[ni] * inv;
                    int d = ni * 16 + lr;
                    int j = d >> 1;
                    int f = j & 15;
                    float tc = (j < 16) ? ((float)(lk / 12)) / 12.0f * 32.0f
                                        : ((float)(lk % 12)) / 12.0f * 32.0f;
                    float ang = (float)((double)tc * FREQS16[f]);
                    float c = cosf(ang), s = sinf(ang);
                    float pr = __shfl_xor(u, 1, 64);
                    float o = (lane & 1) ? (pr * s + u * c) : (u * c - pr * s);
                    obase[d] = o;
                }
            } else {
#pragma unroll
                for (int ni = 0; ni < 4; ni++) obase[ni * 16 + lr] = v[ni];
            }
        }
    }
}

// ---------------------------------------------------------------------------
// Attention: block = (b, h, 64 q-rows). q fp16 -> fp32 LDS; K then V staged
// in the same LDS buffer. Thread (lt=tid>>2, c=tid&3) owns row lt, lk-range
// [c*36, c*36+36). Softmax in registers (4-lane shuffles). Output = fp16
// attn_out written IN-PLACE over the q fp16 slots this block staged (same 2B
// slot, barrier-ordered, blocks disjoint).
// ---------------------------------------------------------------------------
__global__ __launch_bounds__(256) void attn(const f16* qrope,
                                            const float* __restrict__ krope,
                                            const float* __restrict__ v,
                                            const float* __restrict__ abias,
                                            f16* aout) {
    const int L = 1704;
    __shared__ f32x4 qs[64][17];
    __shared__ f32x4 kvs[144][17];
    int bidx = blockIdx.x;
    int ltile = bidx % 27;
    int bh = bidx / 27;
    int h = bh & 15, b = bh >> 4;
    int l0 = ltile * 64;
    int rows = min(64, L - l0);
    int tid = threadIdx.x;

    {
        const f16* qbase = qrope + (long)b * L * 1024 + h * 64;
        for (int i = tid; i < 64 * 16; i += 256) {
            int r = i >> 4, d4 = i & 15;
            int rr = (r < rows) ? r : 0;
            f16x4 hv = *reinterpret_cast<const f16x4*>(qbase + (long)(l0 + rr) * 1024 + d4 * 4);
            f32x4 fv = {(float)hv[0], (float)hv[1], (float)hv[2], (float)hv[3]};
            qs[r][d4] = fv;
        }
        const float* kbase = krope + ((long)(b * 16 + h)) * 144 * 64;
        for (int i = tid; i < 144 * 16; i += 256) {
            int r = i >> 4, d4 = i & 15;
            kvs[r][d4] = *reinterpret_cast<const f32x4*>(kbase + r * 64 + d4 * 4);
        }
    }
    __syncthreads();

    int lt = tid >> 2, c = tid & 3;
    int ltc = (lt < rows) ? lt : 0;
    const float* brow = abias + (long)(l0 + ltc) * 144 + c * 36;

    float p[36];
#pragma unroll
    for (int g = 0; g < 9; g++) {
        int lk = c * 36 + g * 4;
        f32x4 s0 = {0.f, 0.f, 0.f, 0.f}, s1 = {0.f, 0.f, 0.f, 0.f};
        f32x4 s2 = {0.f, 0.f, 0.f, 0.f}, s3 = {0.f, 0.f, 0.f, 0.f};
#pragma unroll
        for (int d4 = 0; d4 < 16; d4++) {
            f32x4 qv = qs[lt][d4];
            s0 += qv * kvs[lk][d4];
            s1 += qv * kvs[lk + 1][d4];
            s2 += qv * kvs[lk + 2][d4];
            s3 += qv * kvs[lk + 3][d4];
        }
        p[g * 4 + 0] = s0.x + s0.y + s0.z + s0.w + brow[g * 4 + 0];
        p[g * 4 + 1] = s1.x + s1.y + s1.z + s1.w + brow[g * 4 + 1];
        p[g * 4 + 2] = s2.x + s2.y + s2.z + s2.w + brow[g * 4 + 2];
        p[g * 4 + 3] = s3.x + s3.y + s3.z + s3.w + brow[g * 4 + 3];
    }

    float mx = -3.0e38f;
#pragma unroll
    for (int j = 0; j < 36; j++) mx = fmaxf(mx, p[j]);
    mx = fmaxf(mx, __shfl_xor(mx, 1, 64));
    mx = fmaxf(mx, __shfl_xor(mx, 2, 64));
    float sum = 0.f;
#pragma unroll
    for (int j = 0; j < 36; j++) {
        p[j] = __expf(p[j] - mx);
        sum += p[j];
    }
    sum += __shfl_xor(sum, 1, 64);
    sum += __shfl_xor(sum, 2, 64);
    float inv = 1.0f / sum;
#pragma unroll
    for (int j = 0; j < 36; j++) p[j] *= inv;

    __syncthreads();  // K reads done before overwrite with V
    {
        const float* vbase = v + ((long)(b * 16 + h)) * 144 * 64;
        for (int i = tid; i < 144 * 16; i += 256) {
            int r = i >> 4, d4 = i & 15;
            kvs[r][d4] = *reinterpret_cast<const f32x4*>(vbase + r * 64 + d4 * 4);
        }
    }
    __syncthreads();

    f32x4 oa[16];
#pragma unroll
    for (int i = 0; i < 16; i++) oa[i] = (f32x4){0.f, 0.f, 0.f, 0.f};
#pragma unroll
    for (int j = 0; j < 36; j++) {
        float pv = p[j];
        int lk = c * 36 + j;
#pragma unroll
        for (int d4 = 0; d4 < 16; d4++) oa[d4] += pv * kvs[lk][d4];
    }
#pragma unroll
    for (int d4 = 0; d4 < 16; d4++) {
        oa[d4].x += __shfl_xor(oa[d4].x, 1, 64); oa[d4].x += __shfl_xor(oa[d4].x, 2, 64);
        oa[d4].y += __shfl_xor(oa[d4].y, 1, 64); oa[d4].y += __shfl_xor(oa[d4].y, 2, 64);
        oa[d4].z += __shfl_xor(oa[d4].z, 1, 64); oa[d4].z += __shfl_xor(oa[d4].z, 2, 64);
        oa[d4].w += __shfl_xor(oa[d4].w, 1, 64); oa[d4].w += __shfl_xor(oa[d4].w, 2, 64);
    }

    if (lt < rows) {
        f16* ao = aout + ((long)(b * L + l0 + lt)) * 1024 + h * 64;
#pragma unroll
        for (int q4 = 0; q4 < 4; q4++) {
            int d4 = c * 4 + q4;
            f16x4 pk = {(f16)oa[d4].x, (f16)oa[d4].y, (f16)oa[d4].z, (f16)oa[d4].w};
            *reinterpret_cast<f16x4*>(ao + d4 * 4) = pk;
        }
    }
}

// ---------------------------------------------------------------------------
// Final projection: out = attn_out(fp16) @ Wproj^T + b_proj, fp32 out.
// A loaded directly as f16x8; W fp32 converted to fp16 on the fly.
// ---------------------------------------------------------------------------
__global__ __launch_bounds__(256) void gemm_proj(const f16* __restrict__ A,
                                                 const float* __restrict__ W,
                                                 const float* __restrict__ bias,
                                                 float* __restrict__ out) {
    const int K = 1024;
    int lane = threadIdx.x & 63, wv = threadIdx.x >> 6;
    int mt = blockIdx.x >> 2;
    int nt = (blockIdx.x & 3) * 4 + wv;
    int lr = lane & 15, quad = lane >> 4;
    long m0 = (long)mt * 64, n0 = (long)nt * 64;

    const f16x8* arow[4];
    const float* wrow[4];
#pragma unroll
    for (int i = 0; i < 4; i++) {
        arow[i] = reinterpret_cast<const f16x8*>(A + (m0 + i * 16 + lr) * K) + quad;
        wrow[i] = W + ((long)(n0 + i * 16 + lr)) * K + quad * 8;
    }

    f32x4 acc[4][4] = {};
    for (int ks = 0; ks < 32; ks++) {
        f16x8 af[4], wh[4];
#pragma unroll
        for (int i = 0; i < 4; i++) {
            af[i] = arow[i][ks * 4];
            const float* wp = wrow[i] + ks * 32;
            wh[i] = cvt8h(*(const f32x4*)wp, *(const f32x4*)(wp + 4));
        }
#pragma unroll
        for (int mi = 0; mi < 4; mi++)
#pragma unroll
            for (int ni = 0; ni < 4; ni++)
                acc[mi][ni] = __builtin_amdgcn_mfma_f32_16x16x32_f16(af[mi], wh[ni], acc[mi][ni], 0, 0, 0);
    }

#pragma unroll
    for (int ni = 0; ni < 4; ni++) {
        int col = (int)n0 + ni * 16 + lr;
        float b = bias[col];
#pragma unroll
        for (int mi = 0; mi < 4; mi++) {
            long row = m0 + mi * 16 + quad * 4;
#pragma unroll
            for (int r = 0; r < 4; r++)
                out[(row + r) * 1024 + col] = acc[mi][ni][r] + b;
        }
    }
}

extern "C" void kernel_launch(void* const* d_in, const int* in_sizes, int n_in,
                              void* d_out, int out_size, void* d_ws, size_t ws_size,
                              hipStream_t stream) {
    const float* x     = (const float*)d_in[0];
    const float* y     = (const float*)d_in[1];
    const float* fc    = (const float*)d_in[2];
    const float* abias = (const float*)d_in[3];
    const float* Wq    = (const float*)d_in[4];
    const float* qb    = (const float*)d_in[5];
    const float* Wkv   = (const float*)d_in[6];
    const float* vb    = (const float*)d_in[7];
    const float* Wp    = (const float*)d_in[8];
    const float* bp    = (const float*)d_in[9];
    const float* smul  = (const float*)d_in[10];

    // d_ws: q buffer, fp16 (13,959,168 * 2 B = 27.9 MB). attn overwrites it
    // in-place with fp16 attn_out (same slots).
    f16* qbuf = (f16*)d_ws;
    // d_out (fp32, 55.8 MB) doubles as KV scratch until gemm_proj overwrites:
    // k_rope 1,179,648 f32 (4.7 MB) + vbuf 1,179,648 f32 (4.7 MB).
    float* k_rope = (float*)d_out;
    float* vbuf   = k_rope + 1179648L;

    dim3 blk(256);
    gemm_q<<<dim3(852), blk, 0, stream>>>(x, Wq, qb, fc, smul, qbuf);
    gemm_kv<<<dim3(144), blk, 0, stream>>>(y, Wkv, vb, k_rope, vbuf);
    attn<<<dim3(3456), blk, 0, stream>>>(qbuf, k_rope, vbuf, abias, (f16*)qbuf);
    gemm_proj<<<dim3(852), blk, 0, stream>>>((const f16*)qbuf, Wp, bp, (float*)d_out);
}

// Round 5
// 861.858 us; speedup vs baseline: 1.1255x; 1.1255x over previous
//
#include <hip/hip_runtime.h>

using u16 = unsigned short;
using u32 = unsigned int;

typedef __bf16 bf16x8 __attribute__((ext_vector_type(8)));
typedef float  f32x4  __attribute__((ext_vector_type(4)));
typedef _Float16 f16;
typedef _Float16 f16x4 __attribute__((ext_vector_type(4)));
typedef _Float16 f16x8 __attribute__((ext_vector_type(8)));
typedef u16 u16x4 __attribute__((ext_vector_type(4)));

__device__ __forceinline__ float b2f(u16 u) { return __uint_as_float(((u32)u) << 16); }
__device__ __forceinline__ u16 f2b(float f) {
    u32 u = __float_as_uint(f);
    return (u16)((u + 0x7FFFu + ((u >> 16) & 1u)) >> 16);  // RNE
}

// ---------------------------------------------------------------------------
// Prep: fp32 -> (hi, lo) bf16 planes, one element converted exactly once.
// hi = RNE(f); lo = RNE(f - hi). hi+lo == f to ~2^-18 rel.
// ---------------------------------------------------------------------------
__global__ __launch_bounds__(256) void split_f32(const float* __restrict__ src,
                                                 u16* __restrict__ hi,
                                                 u16* __restrict__ lo, int n4) {
    int i = blockIdx.x * 256 + threadIdx.x;
    if (i >= n4) return;
    f32x4 v = reinterpret_cast<const f32x4*>(src)[i];
    u16x4 H, L;
#pragma unroll
    for (int j = 0; j < 4; j++) {
        u16 hb = f2b(v[j]);
        H[j] = hb;
        L[j] = f2b(v[j] - b2f(hb));
    }
    reinterpret_cast<u16x4*>(hi)[i] = H;
    reinterpret_cast<u16x4*>(lo)[i] = L;
}

__global__ __launch_bounds__(256) void cvt_f16(const float* __restrict__ src,
                                               f16* __restrict__ dst, int n4) {
    int i = blockIdx.x * 256 + threadIdx.x;
    if (i >= n4) return;
    f32x4 v = reinterpret_cast<const f32x4*>(src)[i];
    f16x4 h = {(f16)v[0], (f16)v[1], (f16)v[2], (f16)v[3]};
    reinterpret_cast<f16x4*>(dst)[i] = h;
}

// fp32x8 -> (hi, lo) bf16x8 (still used by gemm_kv only)
__device__ __forceinline__ void split8(f32x4 a0, f32x4 a1, bf16x8& hi, bf16x8& lo) {
    union { bf16x8 v; u16 s[8]; } H, L;
#pragma unroll
    for (int j = 0; j < 4; j++) {
        float f = a0[j]; u16 hb = f2b(f); H.s[j] = hb;     L.s[j] = f2b(f - b2f(hb));
        float g = a1[j]; u16 gb = f2b(g); H.s[4 + j] = gb; L.s[4 + j] = f2b(g - b2f(gb));
    }
    hi = H.v; lo = L.v;
}

// ---------------------------------------------------------------------------
// Fused q projection: q = x@Wq^T + qb (pre-split bf16 hi/lo planes, 3-MFMA
// fp32-accurate), then per-head L2 norm, * exp(min(smul,ln100)), RoPE.
// Wave = 64 rows x one head. Output fp16 [B*L, 1024].
// Layouts (m89/m91): A lane holds A[m=lane&15][k=quad*8+j];
// C/D row=quad*4+reg, col=lane&15.
// ---------------------------------------------------------------------------
__global__ __launch_bounds__(256) void gemm_q(const u16* __restrict__ xhi,
                                              const u16* __restrict__ xlo,
                                              const u16* __restrict__ whi,
                                              const u16* __restrict__ wlo,
                                              const float* __restrict__ qb,
                                              const float* __restrict__ fc,
                                              const float* __restrict__ smul,
                                              f16* __restrict__ qout) {
    const int K = 1024, L = 1704;
    int lane = threadIdx.x & 63, wv = threadIdx.x >> 6;
    int mt = blockIdx.x >> 2;
    int h  = (blockIdx.x & 3) * 4 + wv;
    int lr = lane & 15, quad = lane >> 4;
    long m0 = (long)mt * 64;

    const bf16x8 *ah_p[4], *al_p[4], *wh_p[4], *wl_p[4];
#pragma unroll
    for (int i = 0; i < 4; i++) {
        long aoff = (m0 + i * 16 + lr) * K;
        long woff = ((long)(h * 64 + i * 16 + lr)) * K;
        ah_p[i] = reinterpret_cast<const bf16x8*>(xhi + aoff) + quad;
        al_p[i] = reinterpret_cast<const bf16x8*>(xlo + aoff) + quad;
        wh_p[i] = reinterpret_cast<const bf16x8*>(whi + woff) + quad;
        wl_p[i] = reinterpret_cast<const bf16x8*>(wlo + woff) + quad;
    }

    f32x4 acc[4][4] = {};
    for (int ks = 0; ks < 32; ks++) {
        bf16x8 AH[4], AL[4], WH[4], WL[4];
#pragma unroll
        for (int i = 0; i < 4; i++) {
            AH[i] = ah_p[i][ks * 4];
            AL[i] = al_p[i][ks * 4];
            WH[i] = wh_p[i][ks * 4];
            WL[i] = wl_p[i][ks * 4];
        }
#pragma unroll
        for (int mi = 0; mi < 4; mi++)
#pragma unroll
            for (int ni = 0; ni < 4; ni++) {
                acc[mi][ni] = __builtin_amdgcn_mfma_f32_16x16x32_bf16(AH[mi], WH[ni], acc[mi][ni], 0, 0, 0);
                acc[mi][ni] = __builtin_amdgcn_mfma_f32_16x16x32_bf16(AL[mi], WH[ni], acc[mi][ni], 0, 0, 0);
                acc[mi][ni] = __builtin_amdgcn_mfma_f32_16x16x32_bf16(AH[mi], WL[ni], acc[mi][ni], 0, 0, 0);
            }
    }

    float sm = __expf(fminf(smul[h], 4.6051702f));  // ln(100)
#pragma unroll
    for (int mi = 0; mi < 4; mi++) {
#pragma unroll
        for (int r = 0; r < 4; r++) {
            long rowg = m0 + mi * 16 + quad * 4 + r;
            float v[4];
            float ss = 0.f;
#pragma unroll
            for (int ni = 0; ni < 4; ni++) {
                v[ni] = acc[mi][ni][r] + qb[h * 64 + ni * 16 + lr];
                ss += v[ni] * v[ni];
            }
            ss += __shfl_xor(ss, 1, 64); ss += __shfl_xor(ss, 2, 64);
            ss += __shfl_xor(ss, 4, 64); ss += __shfl_xor(ss, 8, 64);
            float inv = sm / fmaxf(sqrtf(ss), 1e-12f);
            int l = (int)(rowg % L);
            f16* orow = qout + rowg * 1024 + h * 64;
#pragma unroll
            for (int ni = 0; ni < 4; ni++) {
                float u = v[ni] * inv;
                int d = ni * 16 + lr;
                int j = d >> 1;
                float c = fc[(l * 32 + j) * 2];
                float s = fc[(l * 32 + j) * 2 + 1];
                float pr = __shfl_xor(u, 1, 64);
                float o = (lane & 1) ? (pr * s + u * c) : (u * c - pr * s);
                orow[d] = (f16)o;
            }
        }
    }
}

// freqs for cross RoPE: 10000^(-f/16) = 10^(-f/4)
__constant__ double FREQS16[16] = {
    1.0, 0.5623413251903491, 0.31622776601683794, 0.17782794100389228,
    0.1, 0.05623413251903491, 0.03162277660168379, 0.017782794100389228,
    0.01, 0.005623413251903491, 0.0031622776601683794, 0.0017782794100389228,
    0.001, 0.0005623413251903491, 0.00031622776601683794, 0.00017782794100389228};

// ---------------------------------------------------------------------------
// Fused kv projection: kv = y@Wkv^T (split-bf16 MFMA, in-kernel conversion —
// small kernel, acceptable redundancy). n-tiles 0..15 = k (L2-norm + cross
// RoPE inline); 16..31 = v (+v_bias). Outputs fp32 [B,H,144,64].
// ---------------------------------------------------------------------------
__global__ __launch_bounds__(256) void gemm_kv(const float* __restrict__ y,
                                               const float* __restrict__ Wkv,
                                               const float* __restrict__ vb,
                                               float* __restrict__ kout,
                                               float* __restrict__ vout) {
    const int K = 1024;
    int lane = threadIdx.x & 63, wv = threadIdx.x >> 6;
    int mt = blockIdx.x >> 3;
    int nt = (blockIdx.x & 7) * 4 + wv;
    int lr = lane & 15, quad = lane >> 4;
    long m0 = (long)mt * 64;

    const float* arow[4];
    const float* wrow[4];
#pragma unroll
    for (int i = 0; i < 4; i++) {
        arow[i] = y   + (m0 + i * 16 + lr) * K + quad * 8;
        wrow[i] = Wkv + ((long)(nt * 64 + i * 16 + lr)) * K + quad * 8;
    }

    f32x4 acc[4][4] = {};
    for (int ks = 0; ks < 32; ks++) {
        bf16x8 ah[4], al[4], wh[4], wl[4];
#pragma unroll
        for (int i = 0; i < 4; i++) {
            const float* ap = arow[i] + ks * 32;
            split8(*(const f32x4*)ap, *(const f32x4*)(ap + 4), ah[i], al[i]);
            const float* wp = wrow[i] + ks * 32;
            split8(*(const f32x4*)wp, *(const f32x4*)(wp + 4), wh[i], wl[i]);
        }
#pragma unroll
        for (int mi = 0; mi < 4; mi++)
#pragma unroll
            for (int ni = 0; ni < 4; ni++) {
                acc[mi][ni] = __builtin_amdgcn_mfma_f32_16x16x32_bf16(ah[mi], wh[ni], acc[mi][ni], 0, 0, 0);
                acc[mi][ni] = __builtin_amdgcn_mfma_f32_16x16x32_bf16(al[mi], wh[ni], acc[mi][ni], 0, 0, 0);
                acc[mi][ni] = __builtin_amdgcn_mfma_f32_16x16x32_bf16(ah[mi], wl[ni], acc[mi][ni], 0, 0, 0);
            }
    }

    bool isv = nt >= 16;
    int h = isv ? nt - 16 : nt;
#pragma unroll
    for (int mi = 0; mi < 4; mi++) {
#pragma unroll
        for (int r = 0; r < 4; r++) {
            long row = m0 + mi * 16 + quad * 4 + r;  // [0,1152)
            int b = (int)(row / 144), lk = (int)(row % 144);
            float v[4];
#pragma unroll
            for (int ni = 0; ni < 4; ni++)
                v[ni] = acc[mi][ni][r] + (isv ? vb[h * 64 + ni * 16 + lr] : 0.f);
            float* obase = (isv ? vout : kout) + (((long)(b * 16 + h)) * 144 + lk) * 64;
            if (!isv) {
                float ss = v[0] * v[0] + v[1] * v[1] + v[2] * v[2] + v[3] * v[3];
                ss += __shfl_xor(ss, 1, 64); ss += __shfl_xor(ss, 2, 64);
                ss += __shfl_xor(ss, 4, 64); ss += __shfl_xor(ss, 8, 64);
                float inv = 1.f / fmaxf(sqrtf(ss), 1e-12f);
#pragma unroll
                for (int ni = 0; ni < 4; ni++) {
                    float u = v[ni] * inv;
                    int d = ni * 16 + lr;
                    int j = d >> 1;
                    int f = j & 15;
                    float tc = (j < 16) ? ((float)(lk / 12)) / 12.0f * 32.0f
                                        : ((float)(lk % 12)) / 12.0f * 32.0f;
                    float ang = (float)((double)tc * FREQS16[f]);
                    float c = cosf(ang), s = sinf(ang);
                    float pr = __shfl_xor(u, 1, 64);
                    float o = (lane & 1) ? (pr * s + u * c) : (u * c - pr * s);
                    obase[d] = o;
                }
            } else {
#pragma unroll
                for (int ni = 0; ni < 4; ni++) obase[ni * 16 + lr] = v[ni];
            }
        }
    }
}

// ---------------------------------------------------------------------------
// Attention: block = (b, h, 64 q-rows). q fp16 -> fp32 LDS; K then V staged
// in the same LDS buffer. Thread (lt=tid>>2, c=tid&3) owns row lt, lk-range
// [c*36, c*36+36). Softmax in registers. Output fp16 written IN-PLACE over
// the q slots this block staged (same 2B slot, barrier-ordered, disjoint).
// ---------------------------------------------------------------------------
__global__ __launch_bounds__(256) void attn(const f16* qrope,
                                            const float* __restrict__ krope,
                                            const float* __restrict__ v,
                                            const float* __restrict__ abias,
                                            f16* aout) {
    const int L = 1704;
    __shared__ f32x4 qs[64][17];
    __shared__ f32x4 kvs[144][17];
    int bidx = blockIdx.x;
    int ltile = bidx % 27;
    int bh = bidx / 27;
    int h = bh & 15, b = bh >> 4;
    int l0 = ltile * 64;
    int rows = min(64, L - l0);
    int tid = threadIdx.x;

    {
        const f16* qbase = qrope + (long)b * L * 1024 + h * 64;
        for (int i = tid; i < 64 * 16; i += 256) {
            int r = i >> 4, d4 = i & 15;
            int rr = (r < rows) ? r : 0;
            f16x4 hv = *reinterpret_cast<const f16x4*>(qbase + (long)(l0 + rr) * 1024 + d4 * 4);
            f32x4 fv = {(float)hv[0], (float)hv[1], (float)hv[2], (float)hv[3]};
            qs[r][d4] = fv;
        }
        const float* kbase = krope + ((long)(b * 16 + h)) * 144 * 64;
        for (int i = tid; i < 144 * 16; i += 256) {
            int r = i >> 4, d4 = i & 15;
            kvs[r][d4] = *reinterpret_cast<const f32x4*>(kbase + r * 64 + d4 * 4);
        }
    }
    __syncthreads();

    int lt = tid >> 2, c = tid & 3;
    int ltc = (lt < rows) ? lt : 0;
    const float* brow = abias + (long)(l0 + ltc) * 144 + c * 36;

    float p[36];
#pragma unroll
    for (int g = 0; g < 9; g++) {
        int lk = c * 36 + g * 4;
        f32x4 s0 = {0.f, 0.f, 0.f, 0.f}, s1 = {0.f, 0.f, 0.f, 0.f};
        f32x4 s2 = {0.f, 0.f, 0.f, 0.f}, s3 = {0.f, 0.f, 0.f, 0.f};
#pragma unroll
        for (int d4 = 0; d4 < 16; d4++) {
            f32x4 qv = qs[lt][d4];
            s0 += qv * kvs[lk][d4];
            s1 += qv * kvs[lk + 1][d4];
            s2 += qv * kvs[lk + 2][d4];
            s3 += qv * kvs[lk + 3][d4];
        }
        p[g * 4 + 0] = s0.x + s0.y + s0.z + s0.w + brow[g * 4 + 0];
        p[g * 4 + 1] = s1.x + s1.y + s1.z + s1.w + brow[g * 4 + 1];
        p[g * 4 + 2] = s2.x + s2.y + s2.z + s2.w + brow[g * 4 + 2];
        p[g * 4 + 3] = s3.x + s3.y + s3.z + s3.w + brow[g * 4 + 3];
    }

    float mx = -3.0e38f;
#pragma unroll
    for (int j = 0; j < 36; j++) mx = fmaxf(mx, p[j]);
    mx = fmaxf(mx, __shfl_xor(mx, 1, 64));
    mx = fmaxf(mx, __shfl_xor(mx, 2, 64));
    float sum = 0.f;
#pragma unroll
    for (int j = 0; j < 36; j++) {
        p[j] = __expf(p[j] - mx);
        sum += p[j];
    }
    sum += __shfl_xor(sum, 1, 64);
    sum += __shfl_xor(sum, 2, 64);
    float inv = 1.0f / sum;
#pragma unroll
    for (int j = 0; j < 36; j++) p[j] *= inv;

    __syncthreads();  // K reads done before overwrite with V
    {
        const float* vbase = v + ((long)(b * 16 + h)) * 144 * 64;
        for (int i = tid; i < 144 * 16; i += 256) {
            int r = i >> 4, d4 = i & 15;
            kvs[r][d4] = *reinterpret_cast<const f32x4*>(vbase + r * 64 + d4 * 4);
        }
    }
    __syncthreads();

    f32x4 oa[16];
#pragma unroll
    for (int i = 0; i < 16; i++) oa[i] = (f32x4){0.f, 0.f, 0.f, 0.f};
#pragma unroll
    for (int j = 0; j < 36; j++) {
        float pv = p[j];
        int lk = c * 36 + j;
#pragma unroll
        for (int d4 = 0; d4 < 16; d4++) oa[d4] += pv * kvs[lk][d4];
    }
#pragma unroll
    for (int d4 = 0; d4 < 16; d4++) {
        oa[d4].x += __shfl_xor(oa[d4].x, 1, 64); oa[d4].x += __shfl_xor(oa[d4].x, 2, 64);
        oa[d4].y += __shfl_xor(oa[d4].y, 1, 64); oa[d4].y += __shfl_xor(oa[d4].y, 2, 64);
        oa[d4].z += __shfl_xor(oa[d4].z, 1, 64); oa[d4].z += __shfl_xor(oa[d4].z, 2, 64);
        oa[d4].w += __shfl_xor(oa[d4].w, 1, 64); oa[d4].w += __shfl_xor(oa[d4].w, 2, 64);
    }

    if (lt < rows) {
        f16* ao = aout + ((long)(b * L + l0 + lt)) * 1024 + h * 64;
#pragma unroll
        for (int q4 = 0; q4 < 4; q4++) {
            int d4 = c * 4 + q4;
            f16x4 pk = {(f16)oa[d4].x, (f16)oa[d4].y, (f16)oa[d4].z, (f16)oa[d4].w};
            *reinterpret_cast<f16x4*>(ao + d4 * 4) = pk;
        }
    }
}

// ---------------------------------------------------------------------------
// Final projection: out = attn_out(fp16) @ Wproj^T(fp16 pre-converted) + b,
// fp32 out. Pure load+MFMA K-loop.
// ---------------------------------------------------------------------------
__global__ __launch_bounds__(256) void gemm_proj(const f16* __restrict__ A,
                                                 const f16* __restrict__ Wh,
                                                 const float* __restrict__ bias,
                                                 float* __restrict__ out) {
    const int K = 1024;
    int lane = threadIdx.x & 63, wv = threadIdx.x >> 6;
    int mt = blockIdx.x >> 2;
    int nt = (blockIdx.x & 3) * 4 + wv;
    int lr = lane & 15, quad = lane >> 4;
    long m0 = (long)mt * 64, n0 = (long)nt * 64;

    const f16x8* arow[4];
    const f16x8* wrow[4];
#pragma unroll
    for (int i = 0; i < 4; i++) {
        arow[i] = reinterpret_cast<const f16x8*>(A + (m0 + i * 16 + lr) * K) + quad;
        wrow[i] = reinterpret_cast<const f16x8*>(Wh + ((long)(n0 + i * 16 + lr)) * K) + quad;
    }

    f32x4 acc[4][4] = {};
    for (int ks = 0; ks < 32; ks++) {
        f16x8 af[4], wf[4];
#pragma unroll
        for (int i = 0; i < 4; i++) {
            af[i] = arow[i][ks * 4];
            wf[i] = wrow[i][ks * 4];
        }
#pragma unroll
        for (int mi = 0; mi < 4; mi++)
#pragma unroll
            for (int ni = 0; ni < 4; ni++)
                acc[mi][ni] = __builtin_amdgcn_mfma_f32_16x16x32_f16(af[mi], wf[ni], acc[mi][ni], 0, 0, 0);
    }

#pragma unroll
    for (int ni = 0; ni < 4; ni++) {
        int col = (int)n0 + ni * 16 + lr;
        float b = bias[col];
#pragma unroll
        for (int mi = 0; mi < 4; mi++) {
            long row = m0 + mi * 16 + quad * 4;
#pragma unroll
            for (int r = 0; r < 4; r++)
                out[(row + r) * 1024 + col] = acc[mi][ni][r] + b;
        }
    }
}

extern "C" void kernel_launch(void* const* d_in, const int* in_sizes, int n_in,
                              void* d_out, int out_size, void* d_ws, size_t ws_size,
                              hipStream_t stream) {
    const float* x     = (const float*)d_in[0];
    const float* y     = (const float*)d_in[1];
    const float* fc    = (const float*)d_in[2];
    const float* abias = (const float*)d_in[3];
    const float* Wq    = (const float*)d_in[4];
    const float* qb    = (const float*)d_in[5];
    const float* Wkv   = (const float*)d_in[6];
    const float* vb    = (const float*)d_in[7];
    const float* Wp    = (const float*)d_in[8];
    const float* bp    = (const float*)d_in[9];
    const float* smul  = (const float*)d_in[10];

    const long XN = 13959168L;   // 8*1704*1024
    const long WN = 1048576L;    // 1024*1024

    // d_ws layout (33.9 MB): qbuf fp16 | Wq hi | Wq lo | Wp fp16
    f16* qbuf  = (f16*)d_ws;
    u16* wq_hi = (u16*)(qbuf + XN);
    u16* wq_lo = wq_hi + WN;
    f16* wp_h  = (f16*)(wq_lo + WN);

    // d_out (55.8 MB) phase 1: x hi/lo planes (exact fit). Dead after gemm_q.
    u16* x_hi = (u16*)d_out;
    u16* x_lo = x_hi + XN;
    // d_out phase 2 (after gemm_q): KV scratch, overwritten by gemm_proj.
    float* k_rope = (float*)d_out;
    float* vbuf   = k_rope + 1179648L;

    dim3 blk(256);
    split_f32<<<dim3((int)(XN / 4 / 256)), blk, 0, stream>>>(x, x_hi, x_lo, (int)(XN / 4));
    split_f32<<<dim3((int)(WN / 4 / 256)), blk, 0, stream>>>(Wq, wq_hi, wq_lo, (int)(WN / 4));
    cvt_f16  <<<dim3((int)(WN / 4 / 256)), blk, 0, stream>>>(Wp, wp_h, (int)(WN / 4));
    gemm_q<<<dim3(852), blk, 0, stream>>>(x_hi, x_lo, wq_hi, wq_lo, qb, fc, smul, qbuf);
    gemm_kv<<<dim3(144), blk, 0, stream>>>(y, Wkv, vb, k_rope, vbuf);
    attn<<<dim3(3456), blk, 0, stream>>>(qbuf, k_rope, vbuf, abias, (f16*)qbuf);
    gemm_proj<<<dim3(852), blk, 0, stream>>>((const f16*)qbuf, wp_h, bp, (float*)d_out);
}

// Round 6
// 724.310 us; speedup vs baseline: 1.3393x; 1.1899x over previous
//
#include <hip/hip_runtime.h>

using u16 = unsigned short;
using u32 = unsigned int;

typedef __bf16 bf16x8 __attribute__((ext_vector_type(8)));
typedef float  f32x4  __attribute__((ext_vector_type(4)));
typedef _Float16 f16;
typedef _Float16 f16x4 __attribute__((ext_vector_type(4)));
typedef _Float16 f16x8 __attribute__((ext_vector_type(8)));
typedef u16 u16x4 __attribute__((ext_vector_type(4)));

__device__ __forceinline__ float b2f(u16 u) { return __uint_as_float(((u32)u) << 16); }
__device__ __forceinline__ u16 f2b(float f) {
    u32 u = __float_as_uint(f);
    return (u16)((u + 0x7FFFu + ((u >> 16) & 1u)) >> 16);  // RNE
}

// async global->LDS, 16 B per lane. lds dest = wave-uniform base + lane*16;
// we pass per-thread ptrs equal to base + lane*16 so either semantics match.
__device__ __forceinline__ void async_cp16(void* lds, const void* g) {
    __builtin_amdgcn_global_load_lds(
        (const __attribute__((address_space(1))) u32*)g,
        (__attribute__((address_space(3))) u32*)lds, 16, 0, 0);
}

// ---------------------------------------------------------------------------
// Prep: fp32 -> (hi, lo) bf16 planes, one element converted exactly once.
// ---------------------------------------------------------------------------
__global__ __launch_bounds__(256) void split_f32(const float* __restrict__ src,
                                                 u16* __restrict__ hi,
                                                 u16* __restrict__ lo, int n4) {
    int i = blockIdx.x * 256 + threadIdx.x;
    if (i >= n4) return;
    f32x4 v = reinterpret_cast<const f32x4*>(src)[i];
    u16x4 H, L;
#pragma unroll
    for (int j = 0; j < 4; j++) {
        u16 hb = f2b(v[j]);
        H[j] = hb;
        L[j] = f2b(v[j] - b2f(hb));
    }
    reinterpret_cast<u16x4*>(hi)[i] = H;
    reinterpret_cast<u16x4*>(lo)[i] = L;
}

__global__ __launch_bounds__(256) void cvt_f16(const float* __restrict__ src,
                                               f16* __restrict__ dst, int n4) {
    int i = blockIdx.x * 256 + threadIdx.x;
    if (i >= n4) return;
    f32x4 v = reinterpret_cast<const f32x4*>(src)[i];
    f16x4 h = {(f16)v[0], (f16)v[1], (f16)v[2], (f16)v[3]};
    reinterpret_cast<f16x4*>(dst)[i] = h;
}

// fp32x8 -> (hi, lo) bf16x8 (used by gemm_kv only)
__device__ __forceinline__ void split8(f32x4 a0, f32x4 a1, bf16x8& hi, bf16x8& lo) {
    union { bf16x8 v; u16 s[8]; } H, L;
#pragma unroll
    for (int j = 0; j < 4; j++) {
        float f = a0[j]; u16 hb = f2b(f); H.s[j] = hb;     L.s[j] = f2b(f - b2f(hb));
        float g = a1[j]; u16 gb = f2b(g); H.s[4 + j] = gb; L.s[4 + j] = f2b(g - b2f(gb));
    }
    hi = H.v; lo = L.v;
}

// ---------------------------------------------------------------------------
// Fused q projection, m97-style staging.
// Block = 512 thr (8 waves = heads hg*8..hg*8+7), rows m0..m0+63.
// x-hi/lo staged to LDS per BK=64 chunk (global_load_lds x16B, dbl-buffered);
// W per-wave direct (L2-resident). 3-MFMA hi/lo split (fp32-accurate), then
// per-head L2 norm, * exp(min(smul,ln100)), RoPE. Output fp16 [B*L,1024].
// Layouts (m89/m91): A lane holds A[m=lane&15][k=quad*8+j];
// C/D row=quad*4+reg, col=lane&15.
// ---------------------------------------------------------------------------
__global__ __launch_bounds__(512) void gemm_q(const u16* __restrict__ xhi,
                                              const u16* __restrict__ xlo,
                                              const u16* __restrict__ whi,
                                              const u16* __restrict__ wlo,
                                              const float* __restrict__ qb,
                                              const float* __restrict__ fc,
                                              const float* __restrict__ smul,
                                              f16* __restrict__ qout) {
    const int K = 1024, L = 1704;
    __shared__ u16 xs[2][2][64][64];  // [buf][plane][row][k] = 32 KB
    int tid = threadIdx.x;
    int lane = tid & 63, wv = tid >> 6;        // wv = 0..7
    int mt = blockIdx.x >> 1;
    int hg = blockIdx.x & 1;
    int h  = hg * 8 + wv;
    int lr = lane & 15, quad = lane >> 4;
    long m0 = (long)mt * 64;

    // staging addresses: thread t covers row=t/8, k-elems (t%8)*8..+8
    int srow = tid >> 3, scol = (tid & 7) * 8;
    const u16* g_hi = xhi + (m0 + srow) * K + scol;
    const u16* g_lo = xlo + (m0 + srow) * K + scol;
    u16* l_hi0 = &xs[0][0][srow][scol];
    u16* l_lo0 = &xs[0][1][srow][scol];
    u16* l_hi1 = &xs[1][0][srow][scol];
    u16* l_lo1 = &xs[1][1][srow][scol];

    const bf16x8* wh_p[4];
    const bf16x8* wl_p[4];
#pragma unroll
    for (int i = 0; i < 4; i++) {
        long woff = ((long)(h * 64 + i * 16 + lr)) * K;
        wh_p[i] = reinterpret_cast<const bf16x8*>(whi + woff) + quad;
        wl_p[i] = reinterpret_cast<const bf16x8*>(wlo + woff) + quad;
    }

    f32x4 acc[4][4] = {};

    // prologue: stage chunk 0 into buf 0
    async_cp16(l_hi0, g_hi);
    async_cp16(l_lo0, g_lo);
    __syncthreads();

    for (int c = 0; c < 16; c++) {
        // fire next chunk into the other buffer
        if (c < 15) {
            const u16* gh = g_hi + (c + 1) * 64;
            const u16* gl = g_lo + (c + 1) * 64;
            if (c & 1) { async_cp16(l_hi0, gh); async_cp16(l_lo0, gl); }
            else       { async_cp16(l_hi1, gh); async_cp16(l_lo1, gl); }
        }
        int buf = c & 1;
#pragma unroll
        for (int s = 0; s < 2; s++) {
            bf16x8 AH[4], AL[4], WH[4], WL[4];
#pragma unroll
            for (int i = 0; i < 4; i++) {
                WH[i] = wh_p[i][c * 8 + s * 4];
                WL[i] = wl_p[i][c * 8 + s * 4];
            }
#pragma unroll
            for (int i = 0; i < 4; i++) {
                AH[i] = *reinterpret_cast<const bf16x8*>(&xs[buf][0][i * 16 + lr][s * 32 + quad * 8]);
                AL[i] = *reinterpret_cast<const bf16x8*>(&xs[buf][1][i * 16 + lr][s * 32 + quad * 8]);
            }
#pragma unroll
            for (int mi = 0; mi < 4; mi++)
#pragma unroll
                for (int ni = 0; ni < 4; ni++) {
                    acc[mi][ni] = __builtin_amdgcn_mfma_f32_16x16x32_bf16(AH[mi], WH[ni], acc[mi][ni], 0, 0, 0);
                    acc[mi][ni] = __builtin_amdgcn_mfma_f32_16x16x32_bf16(AL[mi], WH[ni], acc[mi][ni], 0, 0, 0);
                    acc[mi][ni] = __builtin_amdgcn_mfma_f32_16x16x32_bf16(AH[mi], WL[ni], acc[mi][ni], 0, 0, 0);
                }
        }
        __syncthreads();  // waves done reading buf; staged c+1 drained (vmcnt0)
    }

    float sm = __expf(fminf(smul[h], 4.6051702f));  // ln(100)
#pragma unroll
    for (int mi = 0; mi < 4; mi++) {
#pragma unroll
        for (int r = 0; r < 4; r++) {
            long rowg = m0 + mi * 16 + quad * 4 + r;
            float v[4];
            float ss = 0.f;
#pragma unroll
            for (int ni = 0; ni < 4; ni++) {
                v[ni] = acc[mi][ni][r] + qb[h * 64 + ni * 16 + lr];
                ss += v[ni] * v[ni];
            }
            ss += __shfl_xor(ss, 1, 64); ss += __shfl_xor(ss, 2, 64);
            ss += __shfl_xor(ss, 4, 64); ss += __shfl_xor(ss, 8, 64);
            float inv = sm / fmaxf(sqrtf(ss), 1e-12f);
            int l = (int)(rowg % L);
            f16* orow = qout + rowg * 1024 + h * 64;
#pragma unroll
            for (int ni = 0; ni < 4; ni++) {
                float u = v[ni] * inv;
                int d = ni * 16 + lr;
                int j = d >> 1;
                float c = fc[(l * 32 + j) * 2];
                float s = fc[(l * 32 + j) * 2 + 1];
                float pr = __shfl_xor(u, 1, 64);
                float o = (lane & 1) ? (pr * s + u * c) : (u * c - pr * s);
                orow[d] = (f16)o;
            }
        }
    }
}

// freqs for cross RoPE: 10000^(-f/16) = 10^(-f/4)
__constant__ double FREQS16[16] = {
    1.0, 0.5623413251903491, 0.31622776601683794, 0.17782794100389228,
    0.1, 0.05623413251903491, 0.03162277660168379, 0.017782794100389228,
    0.01, 0.005623413251903491, 0.0031622776601683794, 0.0017782794100389228,
    0.001, 0.0005623413251903491, 0.00031622776601683794, 0.00017782794100389228};

// ---------------------------------------------------------------------------
// Fused kv projection (unchanged): y@Wkv^T split-bf16 in-kernel. n-tiles
// 0..15 = k (norm + cross RoPE); 16..31 = v (+bias). fp32 [B,H,144,64] out.
// ---------------------------------------------------------------------------
__global__ __launch_bounds__(256) void gemm_kv(const float* __restrict__ y,
                                               const float* __restrict__ Wkv,
                                               const float* __restrict__ vb,
                                               float* __restrict__ kout,
                                               float* __restrict__ vout) {
    const int K = 1024;
    int lane = threadIdx.x & 63, wv = threadIdx.x >> 6;
    int mt = blockIdx.x >> 3;
    int nt = (blockIdx.x & 7) * 4 + wv;
    int lr = lane & 15, quad = lane >> 4;
    long m0 = (long)mt * 64;

    const float* arow[4];
    const float* wrow[4];
#pragma unroll
    for (int i = 0; i < 4; i++) {
        arow[i] = y   + (m0 + i * 16 + lr) * K + quad * 8;
        wrow[i] = Wkv + ((long)(nt * 64 + i * 16 + lr)) * K + quad * 8;
    }

    f32x4 acc[4][4] = {};
    for (int ks = 0; ks < 32; ks++) {
        bf16x8 ah[4], al[4], wh[4], wl[4];
#pragma unroll
        for (int i = 0; i < 4; i++) {
            const float* ap = arow[i] + ks * 32;
            split8(*(const f32x4*)ap, *(const f32x4*)(ap + 4), ah[i], al[i]);
            const float* wp = wrow[i] + ks * 32;
            split8(*(const f32x4*)wp, *(const f32x4*)(wp + 4), wh[i], wl[i]);
        }
#pragma unroll
        for (int mi = 0; mi < 4; mi++)
#pragma unroll
            for (int ni = 0; ni < 4; ni++) {
                acc[mi][ni] = __builtin_amdgcn_mfma_f32_16x16x32_bf16(ah[mi], wh[ni], acc[mi][ni], 0, 0, 0);
                acc[mi][ni] = __builtin_amdgcn_mfma_f32_16x16x32_bf16(al[mi], wh[ni], acc[mi][ni], 0, 0, 0);
                acc[mi][ni] = __builtin_amdgcn_mfma_f32_16x16x32_bf16(ah[mi], wl[ni], acc[mi][ni], 0, 0, 0);
            }
    }

    bool isv = nt >= 16;
    int h = isv ? nt - 16 : nt;
#pragma unroll
    for (int mi = 0; mi < 4; mi++) {
#pragma unroll
        for (int r = 0; r < 4; r++) {
            long row = m0 + mi * 16 + quad * 4 + r;  // [0,1152)
            int b = (int)(row / 144), lk = (int)(row % 144);
            float v[4];
#pragma unroll
            for (int ni = 0; ni < 4; ni++)
                v[ni] = acc[mi][ni][r] + (isv ? vb[h * 64 + ni * 16 + lr] : 0.f);
            float* obase = (isv ? vout : kout) + (((long)(b * 16 + h)) * 144 + lk) * 64;
            if (!isv) {
                float ss = v[0] * v[0] + v[1] * v[1] + v[2] * v[2] + v[3] * v[3];
                ss += __shfl_xor(ss, 1, 64); ss += __shfl_xor(ss, 2, 64);
                ss += __shfl_xor(ss, 4, 64); ss += __shfl_xor(ss, 8, 64);
                float inv = 1.f / fmaxf(sqrtf(ss), 1e-12f);
#pragma unroll
                for (int ni = 0; ni < 4; ni++) {
                    float u = v[ni] * inv;
                    int d = ni * 16 + lr;
                    int j = d >> 1;
                    int f = j & 15;
                    float tc = (j < 16) ? ((float)(lk / 12)) / 12.0f * 32.0f
                                        : ((float)(lk % 12)) / 12.0f * 32.0f;
                    float ang = (float)((double)tc * FREQS16[f]);
                    float c = cosf(ang), s = sinf(ang);
                    float pr = __shfl_xor(u, 1, 64);
                    float o = (lane & 1) ? (pr * s + u * c) : (u * c - pr * s);
                    obase[d] = o;
                }
            } else {
#pragma unroll
                for (int ni = 0; ni < 4; ni++) obase[ni * 16 + lr] = v[ni];
            }
        }
    }
}

// ---------------------------------------------------------------------------
// Attention (unchanged): block = (b, h, 64 q-rows); fp32 VALU; output fp16
// in-place over q slots.
// ---------------------------------------------------------------------------
__global__ __launch_bounds__(256) void attn(const f16* qrope,
                                            const float* __restrict__ krope,
                                            const float* __restrict__ v,
                                            const float* __restrict__ abias,
                                            f16* aout) {
    const int L = 1704;
    __shared__ f32x4 qs[64][17];
    __shared__ f32x4 kvs[144][17];
    int bidx = blockIdx.x;
    int ltile = bidx % 27;
    int bh = bidx / 27;
    int h = bh & 15, b = bh >> 4;
    int l0 = ltile * 64;
    int rows = min(64, L - l0);
    int tid = threadIdx.x;

    {
        const f16* qbase = qrope + (long)b * L * 1024 + h * 64;
        for (int i = tid; i < 64 * 16; i += 256) {
            int r = i >> 4, d4 = i & 15;
            int rr = (r < rows) ? r : 0;
            f16x4 hv = *reinterpret_cast<const f16x4*>(qbase + (long)(l0 + rr) * 1024 + d4 * 4);
            f32x4 fv = {(float)hv[0], (float)hv[1], (float)hv[2], (float)hv[3]};
            qs[r][d4] = fv;
        }
        const float* kbase = krope + ((long)(b * 16 + h)) * 144 * 64;
        for (int i = tid; i < 144 * 16; i += 256) {
            int r = i >> 4, d4 = i & 15;
            kvs[r][d4] = *reinterpret_cast<const f32x4*>(kbase + r * 64 + d4 * 4);
        }
    }
    __syncthreads();

    int lt = tid >> 2, c = tid & 3;
    int ltc = (lt < rows) ? lt : 0;
    const float* brow = abias + (long)(l0 + ltc) * 144 + c * 36;

    float p[36];
#pragma unroll
    for (int g = 0; g < 9; g++) {
        int lk = c * 36 + g * 4;
        f32x4 s0 = {0.f, 0.f, 0.f, 0.f}, s1 = {0.f, 0.f, 0.f, 0.f};
        f32x4 s2 = {0.f, 0.f, 0.f, 0.f}, s3 = {0.f, 0.f, 0.f, 0.f};
#pragma unroll
        for (int d4 = 0; d4 < 16; d4++) {
            f32x4 qv = qs[lt][d4];
            s0 += qv * kvs[lk][d4];
            s1 += qv * kvs[lk + 1][d4];
            s2 += qv * kvs[lk + 2][d4];
            s3 += qv * kvs[lk + 3][d4];
        }
        p[g * 4 + 0] = s0.x + s0.y + s0.z + s0.w + brow[g * 4 + 0];
        p[g * 4 + 1] = s1.x + s1.y + s1.z + s1.w + brow[g * 4 + 1];
        p[g * 4 + 2] = s2.x + s2.y + s2.z + s2.w + brow[g * 4 + 2];
        p[g * 4 + 3] = s3.x + s3.y + s3.z + s3.w + brow[g * 4 + 3];
    }

    float mx = -3.0e38f;
#pragma unroll
    for (int j = 0; j < 36; j++) mx = fmaxf(mx, p[j]);
    mx = fmaxf(mx, __shfl_xor(mx, 1, 64));
    mx = fmaxf(mx, __shfl_xor(mx, 2, 64));
    float sum = 0.f;
#pragma unroll
    for (int j = 0; j < 36; j++) {
        p[j] = __expf(p[j] - mx);
        sum += p[j];
    }
    sum += __shfl_xor(sum, 1, 64);
    sum += __shfl_xor(sum, 2, 64);
    float inv = 1.0f / sum;
#pragma unroll
    for (int j = 0; j < 36; j++) p[j] *= inv;

    __syncthreads();  // K reads done before overwrite with V
    {
        const float* vbase = v + ((long)(b * 16 + h)) * 144 * 64;
        for (int i = tid; i < 144 * 16; i += 256) {
            int r = i >> 4, d4 = i & 15;
            kvs[r][d4] = *reinterpret_cast<const f32x4*>(vbase + r * 64 + d4 * 4);
        }
    }
    __syncthreads();

    f32x4 oa[16];
#pragma unroll
    for (int i = 0; i < 16; i++) oa[i] = (f32x4){0.f, 0.f, 0.f, 0.f};
#pragma unroll
    for (int j = 0; j < 36; j++) {
        float pv = p[j];
        int lk = c * 36 + j;
#pragma unroll
        for (int d4 = 0; d4 < 16; d4++) oa[d4] += pv * kvs[lk][d4];
    }
#pragma unroll
    for (int d4 = 0; d4 < 16; d4++) {
        oa[d4].x += __shfl_xor(oa[d4].x, 1, 64); oa[d4].x += __shfl_xor(oa[d4].x, 2, 64);
        oa[d4].y += __shfl_xor(oa[d4].y, 1, 64); oa[d4].y += __shfl_xor(oa[d4].y, 2, 64);
        oa[d4].z += __shfl_xor(oa[d4].z, 1, 64); oa[d4].z += __shfl_xor(oa[d4].z, 2, 64);
        oa[d4].w += __shfl_xor(oa[d4].w, 1, 64); oa[d4].w += __shfl_xor(oa[d4].w, 2, 64);
    }

    if (lt < rows) {
        f16* ao = aout + ((long)(b * L + l0 + lt)) * 1024 + h * 64;
#pragma unroll
        for (int q4 = 0; q4 < 4; q4++) {
            int d4 = c * 4 + q4;
            f16x4 pk = {(f16)oa[d4].x, (f16)oa[d4].y, (f16)oa[d4].z, (f16)oa[d4].w};
            *reinterpret_cast<f16x4*>(ao + d4 * 4) = pk;
        }
    }
}

// ---------------------------------------------------------------------------
// Final projection, m97-style staging. Block = 512 thr (8 waves = 8 col-
// tiles), A fp16 tile staged per BK=64 chunk (dbl-buffered 16 KB), W fp16
// per-wave direct. fp32 out.
// ---------------------------------------------------------------------------
__global__ __launch_bounds__(512) void gemm_proj(const f16* __restrict__ A,
                                                 const f16* __restrict__ Wh,
                                                 const float* __restrict__ bias,
                                                 float* __restrict__ out) {
    const int K = 1024;
    __shared__ f16 as[2][64][64];  // [buf][row][k] = 16 KB
    int tid = threadIdx.x;
    int lane = tid & 63, wv = tid >> 6;
    int mt = blockIdx.x >> 1;
    int cg = blockIdx.x & 1;
    int lr = lane & 15, quad = lane >> 4;
    long m0 = (long)mt * 64;
    long n0 = (long)cg * 512 + wv * 64;

    int srow = tid >> 3, scol = (tid & 7) * 8;
    const f16* g_a = A + (m0 + srow) * K + scol;
    f16* l_a0 = &as[0][srow][scol];
    f16* l_a1 = &as[1][srow][scol];

    const f16x8* wrow[4];
#pragma unroll
    for (int i = 0; i < 4; i++)
        wrow[i] = reinterpret_cast<const f16x8*>(Wh + (n0 + i * 16 + lr) * K) + quad;

    f32x4 acc[4][4] = {};

    async_cp16(l_a0, g_a);
    __syncthreads();

    for (int c = 0; c < 16; c++) {
        if (c < 15) {
            const f16* ga = g_a + (c + 1) * 64;
            if (c & 1) async_cp16(l_a0, ga);
            else       async_cp16(l_a1, ga);
        }
        int buf = c & 1;
#pragma unroll
        for (int s = 0; s < 2; s++) {
            f16x8 af[4], wf[4];
#pragma unroll
            for (int i = 0; i < 4; i++) wf[i] = wrow[i][c * 8 + s * 4];
#pragma unroll
            for (int i = 0; i < 4; i++)
                af[i] = *reinterpret_cast<const f16x8*>(&as[buf][i * 16 + lr][s * 32 + quad * 8]);
#pragma unroll
            for (int mi = 0; mi < 4; mi++)
#pragma unroll
                for (int ni = 0; ni < 4; ni++)
                    acc[mi][ni] = __builtin_amdgcn_mfma_f32_16x16x32_f16(af[mi], wf[ni], acc[mi][ni], 0, 0, 0);
        }
        __syncthreads();
    }

#pragma unroll
    for (int ni = 0; ni < 4; ni++) {
        int col = (int)n0 + ni * 16 + lr;
        float b = bias[col];
#pragma unroll
        for (int mi = 0; mi < 4; mi++) {
            long row = m0 + mi * 16 + quad * 4;
#pragma unroll
            for (int r = 0; r < 4; r++)
                out[(row + r) * 1024 + col] = acc[mi][ni][r] + b;
        }
    }
}

extern "C" void kernel_launch(void* const* d_in, const int* in_sizes, int n_in,
                              void* d_out, int out_size, void* d_ws, size_t ws_size,
                              hipStream_t stream) {
    const float* x     = (const float*)d_in[0];
    const float* y     = (const float*)d_in[1];
    const float* fc    = (const float*)d_in[2];
    const float* abias = (const float*)d_in[3];
    const float* Wq    = (const float*)d_in[4];
    const float* qb    = (const float*)d_in[5];
    const float* Wkv   = (const float*)d_in[6];
    const float* vb    = (const float*)d_in[7];
    const float* Wp    = (const float*)d_in[8];
    const float* bp    = (const float*)d_in[9];
    const float* smul  = (const float*)d_in[10];

    const long XN = 13959168L;   // 8*1704*1024
    const long WN = 1048576L;    // 1024*1024

    // d_ws layout (33.9 MB): qbuf fp16 | Wq hi | Wq lo | Wp fp16
    f16* qbuf  = (f16*)d_ws;
    u16* wq_hi = (u16*)(qbuf + XN);
    u16* wq_lo = wq_hi + WN;
    f16* wp_h  = (f16*)(wq_lo + WN);

    // d_out (55.8 MB) phase 1: x hi/lo planes. Dead after gemm_q.
    u16* x_hi = (u16*)d_out;
    u16* x_lo = x_hi + XN;
    // d_out phase 2: KV scratch, overwritten by gemm_proj.
    float* k_rope = (float*)d_out;
    float* vbuf   = k_rope + 1179648L;

    dim3 blk(256);
    split_f32<<<dim3((int)(XN / 4 / 256)), blk, 0, stream>>>(x, x_hi, x_lo, (int)(XN / 4));
    split_f32<<<dim3((int)(WN / 4 / 256)), blk, 0, stream>>>(Wq, wq_hi, wq_lo, (int)(WN / 4));
    cvt_f16  <<<dim3((int)(WN / 4 / 256)), blk, 0, stream>>>(Wp, wp_h, (int)(WN / 4));
    gemm_q<<<dim3(426), dim3(512), 0, stream>>>(x_hi, x_lo, wq_hi, wq_lo, qb, fc, smul, qbuf);
    gemm_kv<<<dim3(144), blk, 0, stream>>>(y, Wkv, vb, k_rope, vbuf);
    attn<<<dim3(3456), blk, 0, stream>>>(qbuf, k_rope, vbuf, abias, (f16*)qbuf);
    gemm_proj<<<dim3(426), dim3(512), 0, stream>>>((const f16*)qbuf, wp_h, bp, (float*)d_out);
}